// Round 15
// baseline (280.247 us; speedup 1.0000x reference)
//
#include <hip/hip_runtime.h>
#include <math.h>

#define TMC 64   // cells per k_main block (16 per wave)

typedef __attribute__((ext_vector_type(4))) float f32x4;
typedef __attribute__((ext_vector_type(8))) short bf16x8;

#define MFMA16(a,b,c) __builtin_amdgcn_mfma_f32_16x16x32_bf16((a),(b),(c),0,0,0)

__device__ __forceinline__ float sigmoidf_(float x){ return 1.0f/(1.0f + __expf(-x)); }
__device__ __forceinline__ float tanhf_(float x){
  float e = __expf(2.0f*x);
  return 1.0f - 2.0f/(e + 1.0f);
}

__device__ __forceinline__ unsigned short f2bf(float f){
  unsigned u = __float_as_uint(f);
  unsigned r = (u + 0x7FFFu + ((u>>16)&1u)) >> 16;
  return (unsigned short)r;
}
__device__ __forceinline__ unsigned pack2(float a, float b){
  return (unsigned)f2bf(a) | ((unsigned)f2bf(b)<<16);
}
__device__ __forceinline__ float bf2f(unsigned short u){ return __uint_as_float(((unsigned)u)<<16); }

// ---------- fused init: x-precompute (block 0) + weight pack + alive ordinals ----------
__global__ void k_init(const float* __restrict__ x,
                       const float* __restrict__ Wa1, const float* __restrict__ ba1,
                       const float* __restrict__ Wg1, const float* __restrict__ bg1,
                       const float* __restrict__ Wa2, const float* __restrict__ Wg2,
                       const float* __restrict__ ba2, const float* __restrict__ bg2,
                       const float* __restrict__ Wih, const float* __restrict__ Whh,
                       const float* __restrict__ bih, const float* __restrict__ bhh,
                       const int* __restrict__ alive,
                       float* __restrict__ xab, float* __restrict__ b2d, float* __restrict__ brz,
                       ushort* __restrict__ W1f, ushort* __restrict__ W2f,
                       ushort* __restrict__ Wgf, ushort* __restrict__ Whf,
                       float* __restrict__ w64, int* __restrict__ iflg, int n){
  int tid = threadIdx.x;
  if (blockIdx.x == 0){
    __shared__ float sx[64];
    if (tid < 64) sx[tid] = x[tid];
    __syncthreads();
    if (tid < 128){
      const float* w = Wa1 + tid*192;
      float s = ba1[tid];
      #pragma unroll
      for (int i=0;i<64;i++) s += w[i]*sx[i];
      xab[tid] = s;
    } else {
      int j = tid-128;
      const float* w = Wg1 + j*192;
      float s = bg1[j];
      #pragma unroll
      for (int i=0;i<64;i++) s += w[i]*sx[i];
      xab[tid] = s;
    }
    if (tid < 64) b2d[tid] = ba2[tid] - bg2[tid];
    brz[tid] = bih[tid] + bhh[tid];
  }
  int stride = gridDim.x*blockDim.x;
  int t0 = blockIdx.x*blockDim.x + tid;
  for (int i=t0; i<256*128; i+=stride){
    int e=i&7, lane=(i>>3)&63, ks=(i>>9)&3, nt=i>>11;
    int r = nt*16 + (lane&15), k = ks*32 + (lane>>4)*8 + e;
    float v = (r<128) ? Wa1[r*192+64+k] : Wg1[(r-128)*192+64+k];
    W1f[i] = f2bf(v);
  }
  for (int i=t0; i<128*128; i+=stride){
    int e=i&7, lane=(i>>3)&63, ks=(i>>9)&3, nt=i>>11;
    int r = nt*16 + (lane&15), k = ks*32 + (lane>>4)*8 + e;
    float v = (r<64) ? Wa2[r*128+k] : Wg2[(r-64)*128+k];
    W2f[i] = f2bf(v);
  }
  for (int i=t0; i<384*64; i+=stride){
    int e=i&7, lane=(i>>3)&63, ks=(i>>9)&1, nt=i>>10;
    int r = nt*16 + (lane&15), k = ks*32 + (lane>>4)*8 + e;
    Wgf[i] = f2bf(Wih[r*65+k]);
  }
  for (int i=t0; i<384*128; i+=stride){
    int e=i&7, lane=(i>>3)&63, ks=(i>>9)&3, nt=i>>11;
    int r = nt*16 + (lane&15), k = ks*32 + (lane>>4)*8 + e;
    Whf[i] = f2bf(Whh[r*128+k]);
  }
  for (int i=t0; i<384; i+=stride) w64[i] = Wih[i*65+64];
  for (int i=t0; i<n; i+=stride) iflg[alive[i]] = i + 1;
}

// ---------- main MFMA kernel: barrier-free wave-private 16-cell tiles ----------
__global__ __launch_bounds__(256,2) void k_main(
    const float* __restrict__ hiddens, const int* __restrict__ alive,
    const ushort* __restrict__ W1f, const ushort* __restrict__ W2f,
    const ushort* __restrict__ Wgf, const ushort* __restrict__ Whf,
    const float* __restrict__ w64,
    const float* __restrict__ xab, const float* __restrict__ b2d,
    const float* __restrict__ brz,
    const float* __restrict__ bih, const float* __restrict__ bhh,
    float* __restrict__ nh, float* __restrict__ facsum,
    float* __restrict__ recs, unsigned* __restrict__ tmax_u, float* __restrict__ tsum,
    int n, int fs, int nffs)
{
  __shared__ ushort sH[4*16*128];                    // 16 KB: per-wave 4KB slab [16][128] bf16, swizzled
  __shared__ __align__(16) ushort arena[4*16*256];   // 32 KB: per-wave 8KB slab; v1 [16][256] then mih [16][64]
  __shared__ float sNp[4][64];
  __shared__ float sM[4], sS[4], sS2[4];
  __shared__ int   sIdx[64];

  int tid = threadIdx.x;
  int lane = tid & 63;
  int w = tid >> 6;
  int l15 = lane & 15;
  int lg  = lane >> 4;

  int base = blockIdx.x * TMC;
  int nvalid = n - base; if (nvalid > TMC) nvalid = TMC;
  int rbase = w*16;
  int gbase = base + rbase;
  int nvw = nvalid - rbase; if (nvw < 0) nvw = 0; if (nvw > 16) nvw = 16;

  char* whb = (char*)sH    + w*4096;   // wave-private h slab
  char* wvb = (char*)arena + w*8192;   // wave-private v1/mih slab

  // ---- per-wave alive indices (wave-private LDS; no block barrier needed)
  if (lane < 16){
    int t2 = rbase + lane; if (t2 >= nvalid) t2 = nvalid - 1;
    sIdx[rbase + lane] = alive[base + t2];
  }

  // ---- stage h -> bf16 wave slab (swizzled)
  {
    int lr = lane >> 2, c0 = (lane & 3) * 32;
    int idx = sIdx[rbase + lr];
    const float* src = hiddens + (size_t)idx*128 + c0;
    #pragma unroll
    for (int j=0; j<32; j+=8){
      float4 v0 = *(const float4*)(src + j);
      float4 v1 = *(const float4*)(src + j + 4);
      uint4 pk;
      pk.x = pack2(v0.x, v0.y); pk.y = pack2(v0.z, v0.w);
      pk.z = pack2(v1.x, v1.y); pk.w = pack2(v1.z, v1.w);
      int byte = (lr*256 + (c0 + j)*2) ^ ((lr&7)<<4);
      *reinterpret_cast<uint4*>(whb + byte) = pk;
    }
  }

  // ---- GEMM1: v1 = relu(h @ W1h^T + xab); full 256 cols, 16 rows
  {
    f32x4 acc1[16];
    #pragma unroll
    for (int tn=0;tn<16;tn++) acc1[tn] = (f32x4)0.f;
    #pragma unroll
    for (int ks=0; ks<4; ks++){
      bf16x8 a = *reinterpret_cast<const bf16x8*>(whb + ((l15*256 + ks*64 + lg*16) ^ ((l15&7)<<4)));
      #pragma unroll
      for (int tn=0;tn<16;tn++){
        bf16x8 b = *(const bf16x8*)(W1f + (((tn*4 + ks)*64 + lane)<<3));
        acc1[tn] = MFMA16(a, b, acc1[tn]);
      }
    }
    #pragma unroll
    for (int tn=0;tn<16;tn++){
      int col = tn*16 + l15;
      float bias = xab[col];
      #pragma unroll
      for (int r=0;r<4;r++){
        int lr = lg*4 + r;
        float v = fmaxf(acc1[tn][r] + bias, 0.f);
        int byte = (lr*512 + col*2) ^ ((lr&7)<<4);
        *(ushort*)(wvb + byte) = f2bf(v);
      }
    }
  }

  // ---- GEMM2: out = a - g; 64 cols, 16 rows
  float outv[4][4];
  {
    f32x4 accA[4], accG[4];
    #pragma unroll
    for (int tn=0;tn<4;tn++){ accA[tn]=(f32x4)0.f; accG[tn]=(f32x4)0.f; }
    #pragma unroll
    for (int ks=0; ks<4; ks++){
      bf16x8 aA = *reinterpret_cast<const bf16x8*>(wvb + ((l15*512 +       ks*64 + lg*16) ^ ((l15&7)<<4)));
      bf16x8 aG = *reinterpret_cast<const bf16x8*>(wvb + ((l15*512 + 256 + ks*64 + lg*16) ^ ((l15&7)<<4)));
      #pragma unroll
      for (int tn=0;tn<4;tn++){
        bf16x8 bA = *(const bf16x8*)(W2f + ((( tn     *4 + ks)*64 + lane)<<3));
        bf16x8 bG = *(const bf16x8*)(W2f + ((((4+tn)  *4 + ks)*64 + lane)<<3));
        accA[tn] = MFMA16(aA, bA, accA[tn]);
        accG[tn] = MFMA16(aG, bG, accG[tn]);
      }
    }
    #pragma unroll
    for (int tn=0;tn<4;tn++){
      int col = tn*16 + l15;
      float bias = b2d[col];
      #pragma unroll
      for (int r=0;r<4;r++)
        outv[tn][r] = accA[tn][r] - accG[tn][r] + bias;
    }
  }

  // ---- write mem_in bf16 (aliases v1 slab; same-wave ordering via lgkmcnt)
  #pragma unroll
  for (int tn=0;tn<4;tn++){
    int col = tn*16 + l15;
    #pragma unroll
    for (int r=0;r<4;r++){
      int lr = lg*4 + r;
      int byte = (lr*128 + col*2) ^ ((lr&7)<<4);
      *(ushort*)(wvb + byte) = f2bf(outv[tn][r]);
    }
  }

  // ---- wave-local tension + softmax partials
  float t16v[4];
  {
    float p[4];
    #pragma unroll
    for (int r=0;r<4;r++){
      float s = 0.f;
      #pragma unroll
      for (int tn=0;tn<4;tn++) s += outv[tn][r]*outv[tn][r];
      p[r] = s;
    }
    #pragma unroll
    for (int off=1; off<16; off<<=1)
      #pragma unroll
      for (int r=0;r<4;r++) p[r] += __shfl_xor(p[r], off);
    float mw = -1.f, se = 0.f, st = 0.f;
    float ev[4];
    #pragma unroll
    for (int r=0;r<4;r++){
      float t = p[r] * (1.0f/64.0f);
      t16v[r] = t;
      bool valid = (lg*4 + r) < nvw;
      mw = fmaxf(mw, valid ? t : -1.f);
    }
    mw = fmaxf(mw, __shfl_xor(mw, 16));
    mw = fmaxf(mw, __shfl_xor(mw, 32));
    #pragma unroll
    for (int r=0;r<4;r++){
      bool valid = (lg*4 + r) < nvw;
      ev[r] = valid ? __expf(t16v[r] - mw) : 0.f;
      se += ev[r];
      st += valid ? t16v[r] : 0.f;
    }
    se += __shfl_xor(se, 16); se += __shfl_xor(se, 32);
    st += __shfl_xor(st, 16); st += __shfl_xor(st, 32);
    if (lane == 0){ sM[w] = mw; sS[w] = se; sS2[w] = st; }
    // per-wave numerator partials
    #pragma unroll
    for (int tn=0;tn<4;tn++){
      float np = 0.f;
      #pragma unroll
      for (int r=0;r<4;r++) np += ev[r] * outv[tn][r];
      np += __shfl_xor(np, 16);
      np += __shfl_xor(np, 32);
      if (lg == 0) sNp[w][tn*16 + l15] = np;
    }
  }

  // ---- GRU, gate-batched: 128 hidden cols, 16 rows
  {
    f32x4 aR[8], aZ[8], aN[8], aI[8];
    #pragma unroll
    for (int tn=0;tn<8;tn++){
      aR[tn]=(f32x4)0.f; aZ[tn]=(f32x4)0.f; aN[tn]=(f32x4)0.f; aI[tn]=(f32x4)0.f;
    }
    // K=128 over h slab: r, z, hn share A fragments
    #pragma unroll
    for (int ks=0; ks<4; ks++){
      bf16x8 a = *reinterpret_cast<const bf16x8*>(whb + ((l15*256 + ks*64 + lg*16) ^ ((l15&7)<<4)));
      #pragma unroll
      for (int tn=0;tn<8;tn++){
        bf16x8 bR = *(const bf16x8*)(Whf + ((((     tn)*4 + ks)*64 + lane)<<3));
        bf16x8 bZ = *(const bf16x8*)(Whf + ((((8  + tn)*4 + ks)*64 + lane)<<3));
        bf16x8 bN = *(const bf16x8*)(Whf + ((((16 + tn)*4 + ks)*64 + lane)<<3));
        aR[tn] = MFMA16(a, bR, aR[tn]);
        aZ[tn] = MFMA16(a, bZ, aZ[tn]);
        aN[tn] = MFMA16(a, bN, aN[tn]);
      }
    }
    // K=64 over mem_in slab: r, z, inn share A fragments
    #pragma unroll
    for (int ks=0; ks<2; ks++){
      bf16x8 a = *reinterpret_cast<const bf16x8*>(wvb + ((l15*128 + ks*64 + lg*16) ^ ((l15&7)<<4)));
      #pragma unroll
      for (int tn=0;tn<8;tn++){
        bf16x8 bR = *(const bf16x8*)(Wgf + ((((     tn)*2 + ks)*64 + lane)<<3));
        bf16x8 bZ = *(const bf16x8*)(Wgf + ((((8  + tn)*2 + ks)*64 + lane)<<3));
        bf16x8 bI = *(const bf16x8*)(Wgf + ((((16 + tn)*2 + ks)*64 + lane)<<3));
        aR[tn] = MFMA16(a, bR, aR[tn]);
        aZ[tn] = MFMA16(a, bZ, aZ[tn]);
        aI[tn] = MFMA16(a, bI, aI[tn]);
      }
    }

    // ---- epilogue: gate math + direct scatter + faction sums (per wave)
    int last = nvw;
    if (gbase + last > nffs) last = nffs - gbase;
    if (last < 0) last = 0;
    int f0 = (fs > 0 && gbase < nffs) ? gbase / fs : 0;
    bool onefac = (last <= 0) || ((gbase + last - 1) / fs == f0);

    #pragma unroll
    for (int tn=0;tn<8;tn++){
      int col = tn*16 + l15;
      float bR0 = brz[col],      wR = w64[col];
      float bZ0 = brz[128+col],  wZ = w64[128+col];
      float bI0 = bih[256+col],  wI = w64[256+col];
      float bN0 = bhh[256+col];
      float fsum = 0.f;
      #pragma unroll
      for (int r=0;r<4;r++){
        int lr = lg*4 + r;
        float t = t16v[r];
        float rr = sigmoidf_(aR[tn][r] + bR0 + t*wR);
        float zz = sigmoidf_(aZ[tn][r] + bZ0 + t*wZ);
        float nnv = tanhf_(aI[tn][r] + bI0 + t*wI + rr*(aN[tn][r] + bN0));
        int hb = (lr*256 + col*2) ^ ((lr&7)<<4);
        float hv = bf2f(*(const ushort*)(whb + hb));
        float v = (1.f - zz)*nnv + zz*hv;
        if (lr < nvw) nh[(size_t)sIdx[rbase+lr]*128 + col] = v;
        if (onefac){
          if (lr < last) fsum += v;
        } else if (lr < last){
          atomicAdd(&facsum[((gbase+lr)/fs)*128 + col], v);
        }
      }
      if (onefac && last > 0){
        fsum += __shfl_xor(fsum, 16);
        fsum += __shfl_xor(fsum, 32);
        if (lg == 0) atomicAdd(&facsum[f0*128 + col], fsum);
      }
    }
  }

  // ---- single tail barrier: combine 4 per-wave softmax records into block record
  __syncthreads();
  if (w == 0){
    float m0 = sM[0], m1 = sM[1], m2v = sM[2], m3 = sM[3];
    float Mb = fmaxf(fmaxf(m0,m1), fmaxf(m2v,m3));
    float e0 = __expf(m0-Mb), e1 = __expf(m1-Mb), e2 = __expf(m2v-Mb), e3 = __expf(m3-Mb);
    float nb = e0*sNp[0][lane] + e1*sNp[1][lane] + e2*sNp[2][lane] + e3*sNp[3][lane];
    float* rec = recs + (size_t)blockIdx.x*66;
    rec[2+lane] = nb;
    if (lane == 0){
      rec[0] = Mb;
      rec[1] = e0*sS[0] + e1*sS[1] + e2*sS[2] + e3*sS[3];
      atomicMax(tmax_u, __float_as_uint(Mb));   // Mb >= 0 (some valid row per block)
      atomicAdd(tsum, sS2[0]+sS2[1]+sS2[2]+sS2[3]);
    }
  }
}

// ---------- combine per-block softmax records ----------
__global__ void k_comb1(const float* __restrict__ recs, int nrec,
                        const unsigned* __restrict__ tmax_u,
                        float* __restrict__ num, float* __restrict__ S){
  int tid = threadIdx.x;
  int c = tid & 63, rg = tid >> 6;
  float M = __uint_as_float(*tmax_u);
  float acc = 0.f, sacc = 0.f;
  for (int r = blockIdx.x*4 + rg; r < nrec; r += gridDim.x*4){
    const float* rec = recs + (size_t)r*66;
    float e = __expf(rec[0] - M);
    acc += e * rec[2+c];
    if (c == 0) sacc += e * rec[1];
  }
  __shared__ float sn[4][64];
  __shared__ float ss[4];
  sn[rg][c] = acc;
  if (c == 0) ss[rg] = sacc;
  __syncthreads();
  if (tid < 64) atomicAdd(&num[tid], sn[0][tid]+sn[1][tid]+sn[2][tid]+sn[3][tid]);
  if (tid == 64) atomicAdd(S, ss[0]+ss[1]+ss[2]+ss[3]);
}

// ---------- finalize combined / mean_tension / faction means ----------
__global__ void k_final(const float* __restrict__ num, const float* __restrict__ S,
                        const float* __restrict__ tsum, const float* __restrict__ facsum,
                        float* __restrict__ out, float* __restrict__ go, float* __restrict__ fmn,
                        int n, int n_f, int fs){
  int tid = threadIdx.x;
  if (tid < 64) out[tid] = num[tid] / *S;
  else if (tid == 64) out[64] = *tsum / (float)n;
  if (tid >= 128 && n_f >= 2){
    int j = tid - 128;
    float s = 0.f;
    for (int f=0; f<n_f; f++){
      float v = facsum[f*128+j];
      s += v;
      fmn[f*128+j] = v / (float)fs;
    }
    go[j] = s / (float)(n_f*fs);
  }
}

// ---------- fused post-pass: copy non-alive rows + faction RMW on alive rows ----------
__global__ void k_post(const float* __restrict__ hid, const int* __restrict__ iflags,
                       const float* __restrict__ fmn, const float* __restrict__ go,
                       const int* __restrict__ step_p,
                       float* __restrict__ nh, int fs, int dc, int nffs, int total){
  bool debate = (*step_p > 5);
  int stride = gridDim.x*blockDim.x;
  for (int idx = blockIdx.x*blockDim.x + threadIdx.x; idx < total; idx += stride){
    int c = idx >> 5, q = idx & 31, j0 = q*4;
    size_t off = (size_t)c*128 + j0;
    int fl = iflags[c];
    if (fl == 0){
      float4 h4 = *(const float4*)(hid + off);
      nh[off] = h4.x; nh[off+1] = h4.y; nh[off+2] = h4.z; nh[off+3] = h4.w;
    } else {
      int i = fl - 1;
      if (i < nffs){
        float v0 = nh[off], v1 = nh[off+1], v2 = nh[off+2], v3 = nh[off+3];
        int f = i / fs;
        float4 fm4 = *(const float4*)(fmn + f*128 + j0);
        v0 = 0.85f*v0 + 0.15f*fm4.x;
        v1 = 0.85f*v1 + 0.15f*fm4.y;
        v2 = 0.85f*v2 + 0.15f*fm4.z;
        v3 = 0.85f*v3 + 0.15f*fm4.w;
        if (debate && (i - f*fs) < dc){
          float4 g4 = *(const float4*)(go + j0);
          v0 = 0.85f*v0 + 0.15f*g4.x;
          v1 = 0.85f*v1 + 0.15f*g4.y;
          v2 = 0.85f*v2 + 0.15f*g4.z;
          v3 = 0.85f*v3 + 0.15f*g4.w;
        }
        nh[off] = v0; nh[off+1] = v1; nh[off+2] = v2; nh[off+3] = v3;
      }
      // alive beyond faction region: value already correct in nh
    }
  }
}

extern "C" void kernel_launch(void* const* d_in, const int* in_sizes, int n_in,
                              void* d_out, int out_size, void* d_ws, size_t ws_size,
                              hipStream_t stream){
  const float* x    = (const float*)d_in[0];
  const float* hid  = (const float*)d_in[1];
  const float* Wa1  = (const float*)d_in[2];
  const float* ba1  = (const float*)d_in[3];
  const float* Wa2  = (const float*)d_in[4];
  const float* ba2  = (const float*)d_in[5];
  const float* Wg1  = (const float*)d_in[6];
  const float* bg1  = (const float*)d_in[7];
  const float* Wg2  = (const float*)d_in[8];
  const float* bg2  = (const float*)d_in[9];
  const float* Wih  = (const float*)d_in[10];
  const float* Whh  = (const float*)d_in[11];
  const float* bih  = (const float*)d_in[12];
  const float* bhh  = (const float*)d_in[13];
  const int*   alive= (const int*)d_in[14];
  const int*   step = (const int*)d_in[15];

  int n = in_sizes[14];
  int n_cells = in_sizes[1] / 128;
  int n_f = (n/2 < 8) ? n/2 : 8;
  int fs   = (n_f >= 2) ? n / n_f : 0;
  int nffs = (n_f >= 2) ? n_f * fs : 0;
  int dc   = (fs/4 > 1) ? fs/4 : 1;
  int nblocks = (n + TMC - 1) / TMC;

  float* out = (float*)d_out;
  float* nh  = out + 65;          // new_hiddens region (4B-aligned only!)
  float* ws  = (float*)d_ws;

  float* xab   = ws + 0;          // 256
  float* b2d   = ws + 256;        // 64
  float* brz   = ws + 320;        // 256
  float* facs  = ws + 576;        // 1024
  float* num   = ws + 1600;       // 64
  float* Ssum  = ws + 1664;       // 1
  float* tsum  = ws + 1665;       // 1
  unsigned* tmax_u = (unsigned*)(ws + 1666);  // 1 (+1 pad)
  float* go    = ws + 1668;       // 128
  float* fmn   = ws + 1796;       // 1024
  float* w64   = ws + 2820;       // 384
  float* recs  = ws + 3204;       // nblocks*66
  int recs_end = 3204 + ((nblocks*66 + 3) & ~3);
  int* iflags  = (int*)(ws + recs_end);                  // n_cells
  int woff = (recs_end + n_cells + 3) & ~3;
  ushort* W1f  = (ushort*)(ws + woff);                   // 256*128 bf16 = 16384 f
  ushort* W2f  = (ushort*)(ws + woff + 16384);           // 128*128 bf16 = 8192 f
  ushort* Wgf  = (ushort*)(ws + woff + 24576);           // 384*64  bf16 = 12288 f
  ushort* Whf  = (ushort*)(ws + woff + 36864);           // 384*128 bf16 = 24576 f

  // zero atomic accumulators (facs..tmax+pad) and iflags
  hipMemsetAsync(ws + 576, 0, 1092*sizeof(float), stream);
  hipMemsetAsync(iflags, 0, (size_t)n_cells*sizeof(int), stream);

  k_init<<<256,256,0,stream>>>(x, Wa1, ba1, Wg1, bg1, Wa2, Wg2, ba2, bg2,
                               Wih, Whh, bih, bhh, alive,
                               xab, b2d, brz, W1f, W2f, Wgf, Whf, w64, iflags, n);
  k_main<<<nblocks,256,0,stream>>>(hid, alive, W1f, W2f, Wgf, Whf, w64, xab, b2d, brz,
                                   bih, bhh, nh, facs, recs, tmax_u, tsum,
                                   n, fs, nffs);
  k_comb1<<<64,256,0,stream>>>(recs, nblocks, tmax_u, num, Ssum);
  k_final<<<1,256,0,stream>>>(num, Ssum, tsum, facs, out, go, fmn, n, n_f, fs);
  k_post<<<2048,256,0,stream>>>(hid, iflags, fmn, go, step, nh, fs, dc, nffs, n_cells*32);
}